// Round 9
// baseline (33.157 us; speedup 1.0000x reference)
//
#include <hip/hip_runtime.h>
#include <hip/hip_bf16.h>

constexpr int S  = 256;
constexpr int D  = 768;
constexpr int KQ = 4;          // K slices
constexpr int KS = D / KQ;     // 192 per slice
constexpr int CH = 96;         // staged chunk width (2 chunks per slice)
constexpr int NCH = KS / CH;   // 2
constexpr int GROWS = KQ * S;  // 1024 floats: G[((batch*256+row)*4+kq)*256+col]

typedef _Float16 half8  __attribute__((ext_vector_type(8)));
typedef _Float16 half4v __attribute__((ext_vector_type(4)));
typedef float    f32x4  __attribute__((ext_vector_type(4)));

// Gram via MFMA with FUSED fp32->(hi,lo) fp16 split in the staging path.
// G_slice = Ah*Bh^T + Ah*Bl^T + Al*Bh^T (fp32 MFMA accumulate); dropped ll term
// ~2^-22|x|^2 (validated round 8, absmax 0.0).
// Grid (16, 8, 4): x = 64x64 tile (ti*4+tj), y = batch, z = kq. 512 blocks (2/CU).
// K=192 per slice staged in 2 chunks of 96 (LDS 53 KB). Per wave: 72 MFMA.
// Also zeroes cnt[] for stage 2's last-block-finalize protocol.
__global__ __launch_bounds__(256) void gram_kernel(const float* __restrict__ X,
                                                   float* __restrict__ G,
                                                   unsigned* __restrict__ cnt) {
    const int ti    = blockIdx.x >> 2;
    const int tj    = blockIdx.x & 3;
    const int batch = blockIdx.y;
    const int kq    = blockIdx.z;
    const int t     = threadIdx.x;

    if (blockIdx.x == 0 && kq == 0 && t == 0) cnt[batch] = 0u;  // stream-ordered

    const float* Xq = X + (size_t)batch * S * D + kq * KS;

    // stride 104 halfs = 208B (16B-aligned rows); 4 x 13.3 KB = 53 KB
    __shared__ _Float16 Ah[64][104], Al[64][104], Bh[64][104], Bl[64][104];

    const int srow = t >> 2;          // staging row 0..63
    const int skg  = (t & 3) * 24;    // staging k offset (24 floats each)
    const float* pa = Xq + (size_t)(ti * 64 + srow) * D + skg;
    const float* pb = Xq + (size_t)(tj * 64 + srow) * D + skg;

    const int lane = t & 63;
    const int w    = t >> 6;          // wave -> rows 16w..16w+15
    const int frow = lane & 15;
    const int fko  = (lane >> 4) * 8; // fragment k offset (8 halfs)

    f32x4 acc[4] = {};

    for (int ch = 0; ch < NCH; ++ch) {
        __syncthreads();              // previous chunk's LDS reads drained
#pragma unroll
        for (int c = 0; c < 6; ++c) {
            const float4 va = *(const float4*)(pa + ch * CH + c * 4);
            const float4 vb = *(const float4*)(pb + ch * CH + c * 4);
            half4v ha, la, hb, lb;
            ha.x = (_Float16)va.x; la.x = (_Float16)(va.x - (float)ha.x);
            ha.y = (_Float16)va.y; la.y = (_Float16)(va.y - (float)ha.y);
            ha.z = (_Float16)va.z; la.z = (_Float16)(va.z - (float)ha.z);
            ha.w = (_Float16)va.w; la.w = (_Float16)(va.w - (float)ha.w);
            hb.x = (_Float16)vb.x; lb.x = (_Float16)(vb.x - (float)hb.x);
            hb.y = (_Float16)vb.y; lb.y = (_Float16)(vb.y - (float)hb.y);
            hb.z = (_Float16)vb.z; lb.z = (_Float16)(vb.z - (float)hb.z);
            hb.w = (_Float16)vb.w; lb.w = (_Float16)(vb.w - (float)hb.w);
            *(half4v*)&Ah[srow][skg + c * 4] = ha;
            *(half4v*)&Al[srow][skg + c * 4] = la;
            *(half4v*)&Bh[srow][skg + c * 4] = hb;
            *(half4v*)&Bl[srow][skg + c * 4] = lb;
        }
        __syncthreads();
#pragma unroll
        for (int ks = 0; ks < 3; ++ks) {
            const int k0 = ks * 32 + fko;
            const half8 ah = *(const half8*)&Ah[w * 16 + frow][k0];
            const half8 al = *(const half8*)&Al[w * 16 + frow][k0];
#pragma unroll
            for (int n = 0; n < 4; ++n) {
                const half8 bh = *(const half8*)&Bh[n * 16 + frow][k0];
                const half8 bl = *(const half8*)&Bl[n * 16 + frow][k0];
                acc[n] = __builtin_amdgcn_mfma_f32_16x16x32_f16(ah, bh, acc[n], 0, 0, 0);
                acc[n] = __builtin_amdgcn_mfma_f32_16x16x32_f16(ah, bl, acc[n], 0, 0, 0);
                acc[n] = __builtin_amdgcn_mfma_f32_16x16x32_f16(al, bh, acc[n], 0, 0, 0);
            }
        }
    }

    // C/D layout (m89-verified): col = lane&15, row = (lane>>4)*4 + reg.
    float* gout = G + ((size_t)(batch * S + ti * 64 + w * 16 + (lane >> 4) * 4) * KQ + kq) * S
                    + tj * 64 + frow;
#pragma unroll
    for (int n = 0; n < 4; ++n)
#pragma unroll
        for (int r = 0; r < 4; ++r)
            gout[(size_t)r * GROWS + n * 16] = acc[n][r];
}

// Stage 2 (fused vis + P + head): wave handles b = blockIdx.x*4 + wave.
//   vis: contiguous 4-slice row read (4 KB) + triangle guard.
//   P:   p_k = x_b . W[:,k] -> P[b][:], wv[b].
//   Last block per batch (threadfence + counter, 64 bumps/batch) computes
//   logits = sum_s w_s P[s][:] and log_softmax -> d_out.
__global__ __launch_bounds__(256) void visxw_kernel(const float* __restrict__ X,
                                                    const float* __restrict__ Wm,
                                                    const float* __restrict__ G,
                                                    float* __restrict__ P,
                                                    float* __restrict__ wv,
                                                    unsigned* __restrict__ cnt,
                                                    float* __restrict__ out) {
    const int batch = blockIdx.y;
    const int wave  = threadIdx.x >> 6;
    const int lane  = threadIdx.x & 63;
    const int b     = blockIdx.x * 4 + wave;

    // ---- visibility of b from 0: one contiguous 4 KB row block ----
    const float* rbp = G + (size_t)(batch * S + b) * GROWS + 4 * lane;
    float4 s0 = make_float4(0.f, 0.f, 0.f, 0.f), s1 = s0, s2 = s0, s3 = s0;
    if (4 * lane <= b) {            // triangle: lanes past b contribute nothing
        s0 = *(const float4*)(rbp + (size_t)0 * S);
        s1 = *(const float4*)(rbp + (size_t)1 * S);
        s2 = *(const float4*)(rbp + (size_t)2 * S);
        s3 = *(const float4*)(rbp + (size_t)3 * S);
    }
    float4 gs;
    gs.x = (s0.x + s1.x) + (s2.x + s3.x);
    gs.y = (s0.y + s1.y) + (s2.y + s3.y);
    gs.z = (s0.z + s1.z) + (s2.z + s3.z);
    gs.w = (s0.w + s1.w) + (s2.w + s3.w);

    const int bq = b & 3;                       // wave-uniform component select
    float sel = (bq == 0) ? gs.x : ((bq == 1) ? gs.y : ((bq == 2) ? gs.z : gs.w));
    const float gb = __shfl(sel, b >> 2);
    const float g0 = __shfl(gs.x, 0);
    const float denom = (b > 0) ? (float)b : 1.0f;

    bool blocked = false;
    {
        const int c0 = 4 * lane;
#define VTEST(Q, GV) { const int c = c0 + (Q); \
        const float line = gb + ((g0 - gb) * (float)(b - c)) / denom; \
        if (c >= 1 && c < b && (GV) >= line) blocked = true; }
        VTEST(0, gs.x) VTEST(1, gs.y) VTEST(2, gs.z) VTEST(3, gs.w)
#undef VTEST
    }
    const bool visflag = (b >= 1) && !__any(blocked);

    // ---- P[b][:] = x_b @ W ----
    const float* xs = X + ((size_t)batch * S + b) * D;
    float a0 = 0.f, a1 = 0.f, a2 = 0.f, a3 = 0.f;
#pragma unroll
    for (int i = 0; i < 3; ++i) {
        const int d0 = (lane + 64 * i) * 4;
        const float4 xv = *(const float4*)(xs + d0);
        const float xf[4] = {xv.x, xv.y, xv.z, xv.w};
#pragma unroll
        for (int j = 0; j < 4; ++j) {
            const float4 wq = *(const float4*)(Wm + (size_t)(d0 + j) * 4);
            a0 = fmaf(xf[j], wq.x, a0);
            a1 = fmaf(xf[j], wq.y, a1);
            a2 = fmaf(xf[j], wq.z, a2);
            a3 = fmaf(xf[j], wq.w, a3);
        }
    }
#pragma unroll
    for (int off = 32; off; off >>= 1) {
        a0 += __shfl_xor(a0, off);
        a1 += __shfl_xor(a1, off);
        a2 += __shfl_xor(a2, off);
        a3 += __shfl_xor(a3, off);
    }
    if (lane == 0) {
        float4 o = {a0, a1, a2, a3};
        *(float4*)(P + ((size_t)batch * S + b) * 4) = o;
        wv[batch * S + b] = visflag ? 1.0f : 0.0f;
    }

    // ---- last block per batch finalizes the head ----
    __shared__ unsigned lastflag;
    __syncthreads();                 // all 4 waves' P/wv stores issued
    if (threadIdx.x == 0) {
        __threadfence();             // release: P/wv visible device-wide
        const unsigned old = atomicAdd(&cnt[batch], 1u);
        lastflag = (old == 63u) ? 1u : 0u;
    }
    __syncthreads();

    if (lastflag) {
        __threadfence();             // acquire side
        const int k = threadIdx.x >> 6;   // wave k -> logit k
        float sum = 0.f;
#pragma unroll
        for (int i = 0; i < 4; ++i) {
            const int s = lane + 64 * i;
            sum = fmaf(wv[batch * S + s], P[((size_t)batch * S + s) * 4 + k], sum);
        }
#pragma unroll
        for (int off = 32; off; off >>= 1) sum += __shfl_xor(sum, off);

        __shared__ float lsh[4];
        if (lane == 0) lsh[k] = sum;
        __syncthreads();

        if (threadIdx.x == 0) {
            const float l0 = lsh[0], l1 = lsh[1], l2 = lsh[2], l3 = lsh[3];
            const float m = fmaxf(fmaxf(l0, l1), fmaxf(l2, l3));
            const float lse = logf(expf(l0 - m) + expf(l1 - m) +
                                   expf(l2 - m) + expf(l3 - m));
            out[batch * 4 + 0] = l0 - m - lse;
            out[batch * 4 + 1] = l1 - m - lse;
            out[batch * 4 + 2] = l2 - m - lse;
            out[batch * 4 + 3] = l3 - m - lse;
        }
    }
}

extern "C" void kernel_launch(void* const* d_in, const int* in_sizes, int n_in,
                              void* d_out, int out_size, void* d_ws, size_t ws_size,
                              hipStream_t stream) {
    const float* X  = (const float*)d_in[0];   // [8, 256, 768] fp32
    const float* Wm = (const float*)d_in[1];   // [768, 4] fp32
    float* out = (float*)d_out;                // [8, 4] fp32

    float* ws = (float*)d_ws;
    float*    P   = ws;                        // 8192 floats
    float*    wv  = ws + 8192;                 // 2048 floats
    unsigned* cnt = (unsigned*)(ws + 10240);   // 8 uints
    float*    G   = ws + 10304;                // 8*256*4*256 = 2.10M floats (8.4 MB)

    gram_kernel <<<dim3(16, 8, 4), 256, 0, stream>>>(X, G, cnt);
    visxw_kernel<<<dim3(64, 8),    256, 0, stream>>>(X, Wm, G, P, wv, cnt, out);
}